// Round 6
// baseline (776.561 us; speedup 1.0000x reference)
//
#include <hip/hip_runtime.h>
#include <stdint.h>

#define THREADS 256
#define NBLOCKS 8192
#define BR      128

// d_ws layout v2: bf16 weights as MFMA A-fragments, grouped per n-HALF.
// Half-stream h (0/1), 400KB each: [layer0: 16KB][layer1..6: 64KB each].
// Fragment = 1KB: lane (hi*32+ln) holds n = h*128 + ft*32 + ln,
// k = ks*16 + hi*8 + e.  Frag index within a layer = ks*4 + ft.
#define NG2_STRIDE 409600
#define WS_WOUT    819200                // layer7: 16 ks x 1 frag = 16KB
#define WS_TOTAL   (WS_WOUT + 16384)

typedef short bf16x8 __attribute__((ext_vector_type(8)));
typedef float f32x16 __attribute__((ext_vector_type(16)));
typedef float f32x4v __attribute__((ext_vector_type(4)));

__device__ __forceinline__ unsigned short f2bf(float f) {
    union { float f; unsigned int u; } v; v.f = f;
    unsigned int u = v.u;
    u += 0x7fffu + ((u >> 16) & 1u);   // round-to-nearest-even
    return (unsigned short)(u >> 16);
}
__device__ __forceinline__ unsigned int cvt_pk_bf16(float lo, float hi) {
    unsigned int d;
    asm("v_cvt_pk_bf16_f32 %0, %1, %2" : "=v"(d) : "v"(lo), "v"(hi));
    return d;
}

// ---------------------------------------------------------------------------
// prep: fp32 weights -> bf16 MFMA A-fragment half-streams in ws
// ---------------------------------------------------------------------------
__global__ void prep_kernel(const float* __restrict__ W_in,
                            const float* __restrict__ W_hid,
                            const float* __restrict__ W_out,
                            unsigned char* __restrict__ ws) {
    int id = blockIdx.x * 256 + threadIdx.x;
    if (id < 16384) {                        // W_in: k(64 pad) x n(256)
        int n = id & 255, k = id >> 8;
        int h = n >> 7, ft = (n >> 5) & 3, ln = n & 31;
        int ks = k >> 4, hi = (k >> 3) & 1, e = k & 7;
        float v = (k < 40) ? W_in[k * 256 + n] : 0.f;
        *(unsigned short*)(ws + h * NG2_STRIDE + (ks * 4 + ft) * 1024
                           + (hi * 32 + ln) * 16 + e * 2) = f2bf(v);
    } else if (id < 16384 + 393216) {        // W_hid: 6 x k(256) x n(256)
        int e2 = id - 16384;
        int l = e2 >> 16, r = e2 & 65535;
        int k = r >> 8, n = r & 255;
        int ks = k >> 4, hi = (k >> 3) & 1, e = k & 7;
        int h = n >> 7, ft = (n >> 5) & 3, ln = n & 31;
        float v = W_hid[l * 65536 + k * 256 + n];
        *(unsigned short*)(ws + h * NG2_STRIDE + 16384 + l * 65536
                           + (ks * 4 + ft) * 1024
                           + (hi * 32 + ln) * 16 + e * 2) = f2bf(v);
    } else if (id < 16384 + 393216 + 8192) { // W_out: k(256) x n(3 -> 32 pad)
        int e3 = id - 16384 - 393216;
        int n = e3 >> 8, k = e3 & 255;
        int ks = k >> 4, hi = (k >> 3) & 1, e = k & 7;
        float v = (n < 3) ? W_out[k * 3 + n] : 0.f;
        *(unsigned short*)(ws + WS_WOUT + ks * 1024
                           + (hi * 32 + n) * 16 + e * 2) = f2bf(v);
    }
}

// ---------------------------------------------------------------------------
// one layer: wave = 128n x 64r (nf=4, rf=2). A from global, B from LDS,
// compiler-scheduled (R5-proven body structure).
// ---------------------------------------------------------------------------
template <int NC>
__device__ __forceinline__ void layer_pass(const unsigned char* __restrict__ wl,
                                           const float* __restrict__ bp,
                                           unsigned char* actL, f32x16 (&acc)[4][2],
                                           int wn, int wr, int l31,
                                           int hi, int hi16, int swz) {
    // bias -> accumulator init (C/D layout: n = (reg&3) + 8*(reg>>2) + 4*hi)
    #pragma unroll
    for (int tn = 0; tn < 4; ++tn) {
        #pragma unroll
        for (int g4 = 0; g4 < 4; ++g4) {
            f32x4v bv = *(const f32x4v*)(bp + wn * 128 + tn * 32 + g4 * 8 + hi * 4);
            #pragma unroll
            for (int tr = 0; tr < 2; ++tr) {
                #pragma unroll
                for (int j = 0; j < 4; ++j)
                    acc[tn][tr][g4 * 4 + j] = bv[j];
            }
        }
    }

    int io[4];
    #pragma unroll
    for (int kk = 0; kk < 4; ++kk) io[kk] = (kk * 32 + hi16) ^ swz;

    const unsigned char* br0 = actL + (wr * 64      + l31) * 512;
    const unsigned char* br1 = actL + (wr * 64 + 32 + l31) * 512;

    __builtin_amdgcn_s_setprio(1);
    #pragma unroll
    for (int ks = 0; ks < NC * 4; ++ks) {
        const unsigned char* fp = wl + ks * 4096;
        bf16x8 a0 = *(const bf16x8*)(fp);
        bf16x8 a1 = *(const bf16x8*)(fp + 1024);
        bf16x8 a2 = *(const bf16x8*)(fp + 2048);
        bf16x8 a3 = *(const bf16x8*)(fp + 3072);
        const int bo = (ks >> 2) * 128 + io[ks & 3];
        bf16x8 b0 = *(const bf16x8*)(br0 + bo);
        bf16x8 b1 = *(const bf16x8*)(br1 + bo);
        acc[0][0] = __builtin_amdgcn_mfma_f32_32x32x16_bf16(a0, b0, acc[0][0], 0, 0, 0);
        acc[1][0] = __builtin_amdgcn_mfma_f32_32x32x16_bf16(a1, b0, acc[1][0], 0, 0, 0);
        acc[2][0] = __builtin_amdgcn_mfma_f32_32x32x16_bf16(a2, b0, acc[2][0], 0, 0, 0);
        acc[3][0] = __builtin_amdgcn_mfma_f32_32x32x16_bf16(a3, b0, acc[3][0], 0, 0, 0);
        acc[0][1] = __builtin_amdgcn_mfma_f32_32x32x16_bf16(a0, b1, acc[0][1], 0, 0, 0);
        acc[1][1] = __builtin_amdgcn_mfma_f32_32x32x16_bf16(a1, b1, acc[1][1], 0, 0, 0);
        acc[2][1] = __builtin_amdgcn_mfma_f32_32x32x16_bf16(a2, b1, acc[2][1], 0, 0, 0);
        acc[3][1] = __builtin_amdgcn_mfma_f32_32x32x16_bf16(a3, b1, acc[3][1], 0, 0, 0);
    }
    __builtin_amdgcn_s_setprio(0);

    __syncthreads();   // all waves done READING act
    #pragma unroll
    for (int tr = 0; tr < 2; ++tr) {
        unsigned char* rowp = actL + (wr * 64 + tr * 32 + l31) * 512;
        #pragma unroll
        for (int tn = 0; tn < 4; ++tn) {
            #pragma unroll
            for (int g4 = 0; g4 < 4; ++g4) {
                float v0 = fmaxf(acc[tn][tr][g4 * 4 + 0], 0.f);
                float v1 = fmaxf(acc[tn][tr][g4 * 4 + 1], 0.f);
                float v2 = fmaxf(acc[tn][tr][g4 * 4 + 2], 0.f);
                float v3 = fmaxf(acc[tn][tr][g4 * 4 + 3], 0.f);
                int n0b = (wn * 128 + tn * 32 + g4 * 8 + hi * 4) * 2;
                uint2 u; u.x = cvt_pk_bf16(v0, v1); u.y = cvt_pk_bf16(v2, v3);
                *(uint2*)(rowp + (n0b ^ swz)) = u;
            }
        }
    }
    __syncthreads();   // act ready for next layer
}

// ---------------------------------------------------------------------------
// fused MLP: enc -> 7x(GEMM+bias+relu), act in LDS, weights global->reg
// ---------------------------------------------------------------------------
__global__ __launch_bounds__(THREADS, 2)
void nerf_main(const float* __restrict__ x,
               const float* __restrict__ b_in,
               const float* __restrict__ b_hid,
               const float* __restrict__ b_out,
               const unsigned char* __restrict__ ws,
               float* __restrict__ out) {
    __shared__ __align__(16) unsigned char actL[65536];  // bf16 [128][256]

    const int tid  = threadIdx.x;
    const int lane = tid & 63;
    const int wv   = tid >> 6;            // 0..3
    const int wn   = wv & 1;              // n-half
    const int wr   = wv >> 1;             // row-half
    const int l31  = lane & 31;
    const int hi   = lane >> 5;
    const int hi16 = hi << 4;
    const int swz  = (l31 & 7) << 4;      // XOR bank swizzle
    const long gr0 = (long)blockIdx.x * BR;

    // ---- positional encoding (R3/R5-proven body, 2 passes of 64 rows) ----
    #pragma unroll
    for (int pass = 0; pass < 2; ++pass) {
        const int rr = (tid >> 2) + pass * 64;   // 0..127
        const int part = tid & 3;
        const int co = part >> 1, hf = part & 1;
        float xv = x[(gr0 + rr) * 2 + co];
        unsigned char* rowp = actL + rr * 512;
        const int rsw = (rr & 7) << 4;
        const int kb = co * 20 + hf * 10;
        float vv[10];
        #pragma unroll
        for (int f = 0; f < 10; ++f) {
            float ang = xv * (float)(1 << f);
            vv[f] = hf ? __cosf(ang) : __sinf(ang);
        }
        #pragma unroll
        for (int p = 0; p < 5; ++p) {
            unsigned int u = cvt_pk_bf16(vv[2 * p], vv[2 * p + 1]);
            int byte = (kb + 2 * p) * 2;
            *(unsigned int*)(rowp + (byte ^ rsw)) = u;
        }
        int z = 80 + part * 12;           // zero-pad bytes [80,128)
        *(unsigned int*)(rowp + ((z    ) ^ rsw)) = 0u;
        *(unsigned int*)(rowp + ((z + 4) ^ rsw)) = 0u;
        *(unsigned int*)(rowp + ((z + 8) ^ rsw)) = 0u;
    }
    __syncthreads();

    f32x16 acc[4][2];
    const unsigned char* wstream = ws + wn * NG2_STRIDE + lane * 16;

    // layer 0 (k=64, 4 k-steps)
    layer_pass<1>(wstream, b_in, actL, acc, wn, wr, l31, hi, hi16, swz);
    wstream += 16384;

    // layers 1..6
    #pragma unroll 1
    for (int l = 0; l < 6; ++l) {
        layer_pass<4>(wstream, b_hid + l * 256,
                      actL, acc, wn, wr, l31, hi, hi16, swz);
        wstream += 65536;
    }

    // ---- layer 7: [128][256] @ Wt_out[32pad][256] -> tanh/100 -> out ----
    {
        f32x16 c0, c1;
        #pragma unroll
        for (int j = 0; j < 16; ++j) { c0[j] = 0.f; c1[j] = 0.f; }
        const unsigned char* wo   = ws + WS_WOUT + lane * 16;
        const unsigned char* arow = actL + (wv * 32 + l31) * 512;
        #pragma unroll
        for (int kk = 0; kk < 16; ++kk) {
            bf16x8 a = *(const bf16x8*)(wo + kk * 1024);
            bf16x8 b = *(const bf16x8*)(arow + (((kk * 32 + hi16)) ^ swz));
            if (kk & 1) c1 = __builtin_amdgcn_mfma_f32_32x32x16_bf16(a, b, c1, 0, 0, 0);
            else        c0 = __builtin_amdgcn_mfma_f32_32x32x16_bf16(a, b, c0, 0, 0, 0);
        }
        if (hi == 0) {
            long row = gr0 + wv * 32 + l31;
            float* op = out + row * 3;
            #pragma unroll
            for (int j = 0; j < 3; ++j)
                op[j] = tanhf(c0[j] + c1[j] + b_out[j]) * 0.01f;
        }
    }
}

extern "C" void kernel_launch(void* const* d_in, const int* in_sizes, int n_in,
                              void* d_out, int out_size, void* d_ws, size_t ws_size,
                              hipStream_t stream) {
    (void)in_sizes; (void)n_in; (void)out_size;
    const float* x     = (const float*)d_in[0];
    const float* W_in  = (const float*)d_in[1];
    const float* b_in  = (const float*)d_in[2];
    const float* W_hid = (const float*)d_in[3];
    const float* b_hid = (const float*)d_in[4];
    const float* W_out = (const float*)d_in[5];
    const float* b_out = (const float*)d_in[6];
    unsigned char* ws  = (unsigned char*)d_ws;
    float* out = (float*)d_out;

    if (ws_size < (size_t)WS_TOTAL) return;

    prep_kernel<<<1632, 256, 0, stream>>>(W_in, W_hid, W_out, ws);
    nerf_main<<<NBLOCKS, THREADS, 0, stream>>>(x, b_in, b_hid, b_out, ws, out);
}

// Round 7
// 726.068 us; speedup vs baseline: 1.0695x; 1.0695x over previous
//
#include <hip/hip_runtime.h>
#include <stdint.h>

#define THREADS 256
#define NBLOCKS 8192
#define BR      128

// d_ws layout: bf16 weights as MFMA A-fragments, CONTIGUOUS per wave (ng).
// Per-ng stream (200KB): [layer0: 8KB][layer1..6: 32KB each].
// Fragment = 1KB: lane (hi*32+l31) holds n = base_n + l31, k = kk*16 + hi*8 + e.
// Within a layer, frag index = (c*4+kk)*2 + ft  (ft = which 32-neuron half).
#define NG_STRIDE 204800
#define WS_WOUT   819200                 // layer7: 16 kk x 1 frag = 16KB
#define WS_TOTAL  (WS_WOUT + 16384)

typedef short bf16x8 __attribute__((ext_vector_type(8)));
typedef short bf16x4 __attribute__((ext_vector_type(4)));
typedef float f32x16 __attribute__((ext_vector_type(16)));
typedef float f32x4v __attribute__((ext_vector_type(4)));

__device__ __forceinline__ unsigned short f2bf(float f) {
    union { float f; unsigned int u; } v; v.f = f;
    unsigned int u = v.u;
    u += 0x7fffu + ((u >> 16) & 1u);   // round-to-nearest-even
    return (unsigned short)(u >> 16);
}
__device__ __forceinline__ unsigned int cvt_pk_bf16(float lo, float hi) {
    unsigned int d;
    asm("v_cvt_pk_bf16_f32 %0, %1, %2" : "=v"(d) : "v"(lo), "v"(hi));
    return d;
}
// act LDS swizzle: byte offset o of row r stored at o ^ ((r&15)<<3).
// 8B-granular -> read as 2x ds_read_b64: 32 lanes spread over 16 bank-pairs
// (2-way aliasing = free, m136) instead of b128's structural 4-way.
__device__ __forceinline__ bf16x8 ld_act(const unsigned char* lo,
                                         const unsigned char* hi) {
    bf16x4 a = *(const bf16x4*)lo;
    bf16x4 b = *(const bf16x4*)hi;
    return __builtin_shufflevector(a, b, 0, 1, 2, 3, 4, 5, 6, 7);
}

// ---------------------------------------------------------------------------
// prep: fp32 weights -> bf16 MFMA A-fragment streams in ws (same as R3/R5)
// ---------------------------------------------------------------------------
__global__ void prep_kernel(const float* __restrict__ W_in,
                            const float* __restrict__ W_hid,
                            const float* __restrict__ W_out,
                            unsigned char* __restrict__ ws) {
    int id = blockIdx.x * 256 + threadIdx.x;
    if (id < 16384) {                        // W_in: k(64 pad) x n(256)
        int n = id & 255, k = id >> 8;
        int ng = n >> 6, ft = (n >> 5) & 1, ln = n & 31;
        int kk = k >> 4, hi = (k >> 3) & 1, e = k & 7;
        float v = (k < 40) ? W_in[k * 256 + n] : 0.f;
        *(unsigned short*)(ws + ng * NG_STRIDE + (kk * 2 + ft) * 1024
                           + (hi * 32 + ln) * 16 + e * 2) = f2bf(v);
    } else if (id < 16384 + 393216) {        // W_hid: 6 x k(256) x n(256)
        int e2 = id - 16384;
        int l = e2 >> 16, r = e2 & 65535;
        int k = r >> 8, n = r & 255;
        int c = k >> 6, kk = (k >> 4) & 3, hi = (k >> 3) & 1, e = k & 7;
        int ng = n >> 6, ft = (n >> 5) & 1, ln = n & 31;
        float v = W_hid[l * 65536 + k * 256 + n];
        *(unsigned short*)(ws + ng * NG_STRIDE + 8192 + l * 32768
                           + ((c * 4 + kk) * 2 + ft) * 1024
                           + (hi * 32 + ln) * 16 + e * 2) = f2bf(v);
    } else if (id < 16384 + 393216 + 8192) { // W_out: k(256) x n(3 -> 32 pad)
        int e3 = id - 16384 - 393216;
        int n = e3 >> 8, k = e3 & 255;
        int kk = k >> 4, hi = (k >> 3) & 1, e = k & 7;
        float v = (n < 3) ? W_out[k * 3 + n] : 0.f;
        *(unsigned short*)(ws + WS_WOUT + kk * 1024
                           + (hi * 32 + n) * 16 + e * 2) = f2bf(v);
    }
}

// ---------------------------------------------------------------------------
// one layer: wave = 64n x 128r. A from global, B from LDS (2x b64, swizzled),
// compiler-scheduled (R5-proven body structure).
// ---------------------------------------------------------------------------
template <int NC>
__device__ __forceinline__ void layer_pass(const unsigned char* __restrict__ wl,
                                           const float* __restrict__ bp,
                                           unsigned char* actL, f32x16 (&acc)[2][4],
                                           int nblk, int l31,
                                           int hi, int hi16,
                                           int rswz, int rswz2) {
    // bias -> accumulator init (C/D layout: n = (reg&3) + 8*(reg>>2) + 4*hi)
    #pragma unroll
    for (int tn = 0; tn < 2; ++tn) {
        #pragma unroll
        for (int g4 = 0; g4 < 4; ++g4) {
            f32x4v bv = *(const f32x4v*)(bp + nblk + tn * 32 + g4 * 8 + hi * 4);
            #pragma unroll
            for (int tr = 0; tr < 4; ++tr) {
                #pragma unroll
                for (int j = 0; j < 4; ++j)
                    acc[tn][tr][g4 * 4 + j] = bv[j];
            }
        }
    }

    const unsigned char* base = actL + l31 * 512;   // tr handled via +tr*16384 imm

    __builtin_amdgcn_s_setprio(1);
    #pragma unroll
    for (int c = 0; c < NC; ++c) {
        #pragma unroll
        for (int kk = 0; kk < 4; ++kk) {
            const unsigned char* fp = wl + (c * 4 + kk) * 2048;
            bf16x8 a0 = *(const bf16x8*)(fp);
            bf16x8 a1 = *(const bf16x8*)(fp + 1024);
            const int bo  = c * 128 + kk * 32 + hi16;
            const int olo = bo ^ rswz;
            const int ohi = bo ^ rswz2;
            bf16x8 b0 = ld_act(base +           olo, base +           ohi);
            bf16x8 b1 = ld_act(base + 16384   + olo, base + 16384   + ohi);
            bf16x8 b2 = ld_act(base + 32768   + olo, base + 32768   + ohi);
            bf16x8 b3 = ld_act(base + 49152   + olo, base + 49152   + ohi);
            acc[0][0] = __builtin_amdgcn_mfma_f32_32x32x16_bf16(a0, b0, acc[0][0], 0, 0, 0);
            acc[1][0] = __builtin_amdgcn_mfma_f32_32x32x16_bf16(a1, b0, acc[1][0], 0, 0, 0);
            acc[0][1] = __builtin_amdgcn_mfma_f32_32x32x16_bf16(a0, b1, acc[0][1], 0, 0, 0);
            acc[1][1] = __builtin_amdgcn_mfma_f32_32x32x16_bf16(a1, b1, acc[1][1], 0, 0, 0);
            acc[0][2] = __builtin_amdgcn_mfma_f32_32x32x16_bf16(a0, b2, acc[0][2], 0, 0, 0);
            acc[1][2] = __builtin_amdgcn_mfma_f32_32x32x16_bf16(a1, b2, acc[1][2], 0, 0, 0);
            acc[0][3] = __builtin_amdgcn_mfma_f32_32x32x16_bf16(a0, b3, acc[0][3], 0, 0, 0);
            acc[1][3] = __builtin_amdgcn_mfma_f32_32x32x16_bf16(a1, b3, acc[1][3], 0, 0, 0);
        }
    }
    __builtin_amdgcn_s_setprio(0);

    __syncthreads();   // all waves done READING act
    #pragma unroll
    for (int tr = 0; tr < 4; ++tr) {
        unsigned char* rowp = actL + (tr * 32 + l31) * 512;
        #pragma unroll
        for (int tn = 0; tn < 2; ++tn) {
            #pragma unroll
            for (int g4 = 0; g4 < 4; ++g4) {
                float v0 = fmaxf(acc[tn][tr][g4 * 4 + 0], 0.f);
                float v1 = fmaxf(acc[tn][tr][g4 * 4 + 1], 0.f);
                float v2 = fmaxf(acc[tn][tr][g4 * 4 + 2], 0.f);
                float v3 = fmaxf(acc[tn][tr][g4 * 4 + 3], 0.f);
                int n0b = (nblk + tn * 32 + g4 * 8 + hi * 4) * 2;
                uint2 u; u.x = cvt_pk_bf16(v0, v1); u.y = cvt_pk_bf16(v2, v3);
                *(uint2*)(rowp + (n0b ^ rswz)) = u;
            }
        }
    }
    __syncthreads();   // act ready for next layer
}

// ---------------------------------------------------------------------------
// fused MLP: enc -> 7x(GEMM+bias+relu), act in LDS, weights global->reg
// ---------------------------------------------------------------------------
__global__ __launch_bounds__(THREADS, 2)
void nerf_main(const float* __restrict__ x,
               const float* __restrict__ b_in,
               const float* __restrict__ b_hid,
               const float* __restrict__ b_out,
               const unsigned char* __restrict__ ws,
               float* __restrict__ out) {
    __shared__ __align__(16) unsigned char actL[65536];  // bf16 [128][256]

    const int tid  = threadIdx.x;
    const int lane = tid & 63;
    const int wv   = tid >> 6;            // 0..3 (= ng)
    const int l31  = lane & 31;
    const int hi   = lane >> 5;
    const int hi16 = hi << 4;
    const int rswz  = (l31 & 15) << 3;    // 8B-granular act swizzle
    const int rswz2 = rswz ^ 8;
    const int nblk = wv * 64;
    const long gr0 = (long)blockIdx.x * BR;

    // ---- positional encoding (R5 body, 8B-granular swizzle) ----
    #pragma unroll
    for (int pass = 0; pass < 2; ++pass) {
        const int rr = (tid >> 2) + pass * 64;   // 0..127
        const int part = tid & 3;
        const int co = part >> 1, hf = part & 1;
        float xv = x[(gr0 + rr) * 2 + co];
        unsigned char* rowp = actL + rr * 512;
        const int rsw = (rr & 15) << 3;
        const int kb = co * 20 + hf * 10;
        float vv[10];
        #pragma unroll
        for (int f = 0; f < 10; ++f) {
            float ang = xv * (float)(1 << f);
            vv[f] = hf ? __cosf(ang) : __sinf(ang);
        }
        #pragma unroll
        for (int p = 0; p < 5; ++p) {
            unsigned int u = cvt_pk_bf16(vv[2 * p], vv[2 * p + 1]);
            int byte = (kb + 2 * p) * 2;
            *(unsigned int*)(rowp + (byte ^ rsw)) = u;
        }
        int z = 80 + part * 12;           // zero-pad bytes [80,128)
        *(unsigned int*)(rowp + ((z    ) ^ rsw)) = 0u;
        *(unsigned int*)(rowp + ((z + 4) ^ rsw)) = 0u;
        *(unsigned int*)(rowp + ((z + 8) ^ rsw)) = 0u;
    }
    __syncthreads();

    f32x16 acc[2][4];
    const unsigned char* wstream = ws + wv * NG_STRIDE + lane * 16;

    // layer 0 (k=64, 1 chunk)
    layer_pass<1>(wstream, b_in, actL, acc, nblk, l31, hi, hi16, rswz, rswz2);
    wstream += 8192;

    // layers 1..6
    #pragma unroll 1
    for (int l = 0; l < 6; ++l) {
        layer_pass<4>(wstream, b_hid + l * 256,
                      actL, acc, nblk, l31, hi, hi16, rswz, rswz2);
        wstream += 32768;
    }

    // ---- layer 7: [128][256] @ Wt_out[32pad][256] -> tanh/100 -> out ----
    {
        f32x16 c0, c1;
        #pragma unroll
        for (int j = 0; j < 16; ++j) { c0[j] = 0.f; c1[j] = 0.f; }
        const unsigned char* wo   = ws + WS_WOUT + lane * 16;
        const unsigned char* arow = actL + (wv * 32 + l31) * 512;
        #pragma unroll
        for (int kk = 0; kk < 16; ++kk) {
            bf16x8 a = *(const bf16x8*)(wo + kk * 1024);
            const int bo = kk * 32 + hi16;
            bf16x8 b = ld_act(arow + (bo ^ rswz), arow + (bo ^ rswz2));
            if (kk & 1) c1 = __builtin_amdgcn_mfma_f32_32x32x16_bf16(a, b, c1, 0, 0, 0);
            else        c0 = __builtin_amdgcn_mfma_f32_32x32x16_bf16(a, b, c0, 0, 0, 0);
        }
        if (hi == 0) {
            long row = gr0 + wv * 32 + l31;
            float* op = out + row * 3;
            #pragma unroll
            for (int j = 0; j < 3; ++j)
                op[j] = tanhf(c0[j] + c1[j] + b_out[j]) * 0.01f;
        }
    }
}

extern "C" void kernel_launch(void* const* d_in, const int* in_sizes, int n_in,
                              void* d_out, int out_size, void* d_ws, size_t ws_size,
                              hipStream_t stream) {
    (void)in_sizes; (void)n_in; (void)out_size;
    const float* x     = (const float*)d_in[0];
    const float* W_in  = (const float*)d_in[1];
    const float* b_in  = (const float*)d_in[2];
    const float* W_hid = (const float*)d_in[3];
    const float* b_hid = (const float*)d_in[4];
    const float* W_out = (const float*)d_in[5];
    const float* b_out = (const float*)d_in[6];
    unsigned char* ws  = (unsigned char*)d_ws;
    float* out = (float*)d_out;

    if (ws_size < (size_t)WS_TOTAL) return;

    prep_kernel<<<1632, 256, 0, stream>>>(W_in, W_hid, W_out, ws);
    nerf_main<<<NBLOCKS, THREADS, 0, stream>>>(x, b_in, b_hid, b_out, ws, out);
}